// Round 3
// baseline (2379.744 us; speedup 1.0000x reference)
//
#include <hip/hip_runtime.h>
#include <hip/hip_bf16.h>

#define NB 16
#define NS 4096
#define ND 256

typedef __attribute__((ext_vector_type(8))) short bfrag;   // 8 bf16 (4 VGPRs)
typedef __attribute__((ext_vector_type(4))) short s16x4;
typedef __attribute__((ext_vector_type(4))) float f32x4;

__device__ __forceinline__ short f2bf(float f) {
    unsigned u = __float_as_uint(f);
    unsigned r = (u + 0x7fffu + ((u >> 16) & 1u)) >> 16;  // RNE, no NaN expected
    return (short)r;
}

__device__ __forceinline__ bfrag pack8(f32x4 a, f32x4 b) {
    bfrag r;
    r[0]=f2bf(a[0]); r[1]=f2bf(a[1]); r[2]=f2bf(a[2]); r[3]=f2bf(a[3]);
    r[4]=f2bf(b[0]); r[5]=f2bf(b[1]); r[6]=f2bf(b[2]); r[7]=f2bf(b[3]);
    return r;
}

__device__ __forceinline__ float sigmoid_f(float z) {
    float t = __builtin_amdgcn_exp2f(-1.44269504f * z);
    return __builtin_amdgcn_rcpf(1.0f + t);
}

// ---------------- Phase 1: x_silu = silu(x @ Wx^T + bx) -> out (f32) --------
__global__ __launch_bounds__(256, 1) void xproj_kernel(
    const float* __restrict__ x, const float* __restrict__ Wx,
    const float* __restrict__ bx, float* __restrict__ out)
{
    __shared__ short xs[64][264];          // +8 pad: conflict-free b128 reads
    const int tid = threadIdx.x;
    const int w = tid >> 6;                // wave 0..3 -> cols w*64..+64
    const int l = tid & 63;
    const int q = l >> 4, r = l & 15;
    const long rbase = (long)blockIdx.x * 64;
    const float* xp = x + rbase * ND;

    #pragma unroll
    for (int i = 0; i < 16; ++i) {
        int flat = i * 1024 + tid * 4;
        f32x4 v = *(const f32x4*)(xp + flat);
        s16x4 s;
        s[0]=f2bf(v[0]); s[1]=f2bf(v[1]); s[2]=f2bf(v[2]); s[3]=f2bf(v[3]);
        *(s16x4*)&xs[flat >> 8][flat & 255] = s;
    }

    bfrag bfr[4][8];
    float bxv[4];
    #pragma unroll
    for (int nt = 0; nt < 4; ++nt) {
        int col = w*64 + nt*16 + r;
        bxv[nt] = bx[col];
        const float* wp = Wx + col * ND + q * 8;
        #pragma unroll
        for (int kt = 0; kt < 8; ++kt) {
            f32x4 f0 = *(const f32x4*)(wp + kt*32);
            f32x4 f1 = *(const f32x4*)(wp + kt*32 + 4);
            bfr[nt][kt] = pack8(f0, f1);
        }
    }
    __syncthreads();

    #pragma unroll
    for (int mt = 0; mt < 4; ++mt) {
        bfrag afr[8];
        #pragma unroll
        for (int kt = 0; kt < 8; ++kt)
            afr[kt] = *(const bfrag*)&xs[mt*16 + r][kt*32 + q*8];
        #pragma unroll
        for (int nt = 0; nt < 4; ++nt) {
            f32x4 acc = {bxv[nt], bxv[nt], bxv[nt], bxv[nt]};
            #pragma unroll
            for (int kt = 0; kt < 8; ++kt)
                acc = __builtin_amdgcn_mfma_f32_16x16x32_bf16(afr[kt], bfr[nt][kt], acc, 0, 0, 0);
            #pragma unroll
            for (int rr = 0; rr < 4; ++rr) {
                float y = acc[rr];
                float sv = y * sigmoid_f(y);               // silu
                long row = rbase + mt*16 + q*4 + rr;       // C: row=(l>>4)*4+reg
                out[row * ND + (w*64 + nt*16 + r)] = sv;   // C: col=l&15
            }
        }
    }
}

// ---------------- Phase 2: serial gated recurrence, 1 block per batch -------
// Wh^T resident in VGPRs as B-frags. A rows replicate h (any C row = answer).
// KEY (round 3): __syncthreads() drains vmcnt(0) every step, so ALL vmem ops
// (h store, xs load) are issued at the START of the step — the ~600cy
// MFMA+tail body covers their latency before the barrier drain.
__global__ __launch_bounds__(256, 1) void scan_kernel(
    const float* __restrict__ Wh, const float* __restrict__ bh,
    float* __restrict__ io /* in: x_silu, out: h_t, in-place */)
{
    __shared__ short hbuf[2][256];
    const int tid = threadIdx.x;
    const int w = tid >> 6;
    const int l = tid & 63;
    const int q = l >> 4, r = l & 15;
    const int b = blockIdx.x;

    // resident B fragments of Wh^T (128 VGPRs)
    bfrag bfr[4][8];
    float bhv0, bhv1, bhv2, bhv3;
    #pragma unroll
    for (int nt = 0; nt < 4; ++nt) {
        int col = w*64 + nt*16 + r;
        float bv = bh[col];
        if (nt == 0) bhv0 = bv; else if (nt == 1) bhv1 = bv;
        else if (nt == 2) bhv2 = bv; else bhv3 = bv;
        const float* wp = Wh + col * ND + q * 8;
        #pragma unroll
        for (int kt = 0; kt < 8; ++kt) {
            f32x4 f0 = *(const f32x4*)(wp + kt*32);
            f32x4 f1 = *(const f32x4*)(wp + kt*32 + 4);
            bfr[nt][kt] = pack8(f0, f1);
        }
    }

    const int j = w*64 + l;                 // this lane's output column == tid
    float* iop = io + (long)b * NS * ND;

    hbuf[0][tid] = 0;                       // h_0 = 0
    __syncthreads();

    float xs_cur = iop[j];                  // xs for t=0
    float hn_prev = 0.0f;
    const float* ld = iop + ND + j;         // next xs load: row t+1
    float*       st = iop + j;              // delayed store: row t-1

    for (int t = 0; t < NS; ++t) {
        const int cur = t & 1, nxt = cur ^ 1;

        // --- issue all memory ops FIRST (cover latency under MFMA+tail) ---
        bfrag afr[8];
        #pragma unroll
        for (int kt = 0; kt < 8; ++kt)
            afr[kt] = *(const bfrag*)&hbuf[cur][kt*32 + q*8];
        if (t) { *st = hn_prev; st += ND; }           // store h[t-1]
        float xs_next = 0.0f;
        if (t + 1 < NS) xs_next = *ld;                // load xs[t+1]
        ld += ND;

        // --- 32 MFMAs: 4 independent K-chains of 8 ---
        f32x4 a0 = {bhv0, bhv0, bhv0, bhv0};
        f32x4 a1 = {bhv1, bhv1, bhv1, bhv1};
        f32x4 a2 = {bhv2, bhv2, bhv2, bhv2};
        f32x4 a3 = {bhv3, bhv3, bhv3, bhv3};
        #pragma unroll
        for (int kt = 0; kt < 8; ++kt) {
            a0 = __builtin_amdgcn_mfma_f32_16x16x32_bf16(afr[kt], bfr[0][kt], a0, 0, 0, 0);
            a1 = __builtin_amdgcn_mfma_f32_16x16x32_bf16(afr[kt], bfr[1][kt], a1, 0, 0, 0);
            a2 = __builtin_amdgcn_mfma_f32_16x16x32_bf16(afr[kt], bfr[2][kt], a2, 0, 0, 0);
            a3 = __builtin_amdgcn_mfma_f32_16x16x32_bf16(afr[kt], bfr[3][kt], a3, 0, 0, 0);
        }

        // --- elementwise tail: 1 value/lane (my tile is nt = q) ---
        float y  = (q & 2) ? ((q & 1) ? a3[0] : a2[0]) : ((q & 1) ? a1[0] : a0[0]);
        float xs = xs_cur;
        float hs = y * sigmoid_f(y);              // silu(h@Wh^T + bh)
        float g  = sigmoid_f(xs + hs);            // gate
        float hn = hs + g * (xs - hs);            // g*xs + (1-g)*hs

        hbuf[nxt][tid] = f2bf(hn);                // h for next step (critical)
        hn_prev = hn;
        xs_cur  = xs_next;
        __syncthreads();
    }
    *st = hn_prev;                                // final store h[NS-1]
}

// ---------------- Phase 3: in-place LayerNorm over last dim ----------------
__global__ __launch_bounds__(256, 4) void ln_kernel(
    const float* __restrict__ gamma, const float* __restrict__ beta,
    float* __restrict__ io)
{
    const long row = (long)blockIdx.x * 4 + (threadIdx.x >> 6);
    const int l = threadIdx.x & 63;
    float* p = io + row * ND + l * 4;
    f32x4 v = *(const f32x4*)p;
    float s  = v[0] + v[1] + v[2] + v[3];
    float s2 = v[0]*v[0] + v[1]*v[1] + v[2]*v[2] + v[3]*v[3];
    #pragma unroll
    for (int off = 32; off; off >>= 1) {
        s  += __shfl_xor(s,  off, 64);
        s2 += __shfl_xor(s2, off, 64);
    }
    float mu  = s * (1.0f / 256.0f);
    float var = s2 * (1.0f / 256.0f) - mu * mu;
    float inv = __builtin_amdgcn_rsqf(var + 1e-5f);
    f32x4 gm = *(const f32x4*)(gamma + l * 4);
    f32x4 bt = *(const f32x4*)(beta  + l * 4);
    f32x4 o;
    #pragma unroll
    for (int i = 0; i < 4; ++i)
        o[i] = (v[i] - mu) * inv * gm[i] + bt[i];
    *(f32x4*)p = o;
}

extern "C" void kernel_launch(void* const* d_in, const int* in_sizes, int n_in,
                              void* d_out, int out_size, void* d_ws, size_t ws_size,
                              hipStream_t stream) {
    (void)in_sizes; (void)n_in; (void)out_size; (void)d_ws; (void)ws_size;
    const float* x     = (const float*)d_in[0];
    const float* Wx    = (const float*)d_in[1];
    const float* bx    = (const float*)d_in[2];
    const float* Wh    = (const float*)d_in[3];
    const float* bh    = (const float*)d_in[4];
    const float* gamma = (const float*)d_in[5];
    const float* beta  = (const float*)d_in[6];
    float* out = (float*)d_out;

    xproj_kernel<<<(NB * NS) / 64, 256, 0, stream>>>(x, Wx, bx, out);
    scan_kernel <<<NB, 256, 0, stream>>>(Wh, bh, out);
    ln_kernel   <<<(NB * NS) / 4, 256, 0, stream>>>(gamma, beta, out);
}

// Round 4
// 1902.041 us; speedup vs baseline: 1.2512x; 1.2512x over previous
//
#include <hip/hip_runtime.h>
#include <hip/hip_bf16.h>

#define NB 16
#define NS 4096
#define ND 256

typedef __attribute__((ext_vector_type(8))) short bfrag;   // 8 bf16 (4 VGPRs)
typedef __attribute__((ext_vector_type(4))) short s16x4;
typedef __attribute__((ext_vector_type(4))) float f32x4;

__device__ __forceinline__ short f2bf(float f) {
    unsigned u = __float_as_uint(f);
    unsigned r = (u + 0x7fffu + ((u >> 16) & 1u)) >> 16;  // RNE, no NaN expected
    return (short)r;
}

__device__ __forceinline__ bfrag pack8(f32x4 a, f32x4 b) {
    bfrag r;
    r[0]=f2bf(a[0]); r[1]=f2bf(a[1]); r[2]=f2bf(a[2]); r[3]=f2bf(a[3]);
    r[4]=f2bf(b[0]); r[5]=f2bf(b[1]); r[6]=f2bf(b[2]); r[7]=f2bf(b[3]);
    return r;
}

__device__ __forceinline__ float sigmoid_f(float z) {
    float t = __builtin_amdgcn_exp2f(-1.44269504f * z);
    return __builtin_amdgcn_rcpf(1.0f + t);
}

// ---------------- Phase 1: x_silu = silu(x @ Wx^T + bx) -> out (f32) --------
__global__ __launch_bounds__(256, 1) void xproj_kernel(
    const float* __restrict__ x, const float* __restrict__ Wx,
    const float* __restrict__ bx, float* __restrict__ out)
{
    __shared__ short xs[64][264];          // +8 pad: conflict-free b128 reads
    const int tid = threadIdx.x;
    const int w = tid >> 6;                // wave 0..3 -> cols w*64..+64
    const int l = tid & 63;
    const int q = l >> 4, r = l & 15;
    const long rbase = (long)blockIdx.x * 64;
    const float* xp = x + rbase * ND;

    #pragma unroll
    for (int i = 0; i < 16; ++i) {
        int flat = i * 1024 + tid * 4;
        f32x4 v = *(const f32x4*)(xp + flat);
        s16x4 s;
        s[0]=f2bf(v[0]); s[1]=f2bf(v[1]); s[2]=f2bf(v[2]); s[3]=f2bf(v[3]);
        *(s16x4*)&xs[flat >> 8][flat & 255] = s;
    }

    bfrag bfr[4][8];
    float bxv[4];
    #pragma unroll
    for (int nt = 0; nt < 4; ++nt) {
        int col = w*64 + nt*16 + r;
        bxv[nt] = bx[col];
        const float* wp = Wx + col * ND + q * 8;
        #pragma unroll
        for (int kt = 0; kt < 8; ++kt) {
            f32x4 f0 = *(const f32x4*)(wp + kt*32);
            f32x4 f1 = *(const f32x4*)(wp + kt*32 + 4);
            bfr[nt][kt] = pack8(f0, f1);
        }
    }
    __syncthreads();

    #pragma unroll
    for (int mt = 0; mt < 4; ++mt) {
        bfrag afr[8];
        #pragma unroll
        for (int kt = 0; kt < 8; ++kt)
            afr[kt] = *(const bfrag*)&xs[mt*16 + r][kt*32 + q*8];
        #pragma unroll
        for (int nt = 0; nt < 4; ++nt) {
            f32x4 acc = {bxv[nt], bxv[nt], bxv[nt], bxv[nt]};
            #pragma unroll
            for (int kt = 0; kt < 8; ++kt)
                acc = __builtin_amdgcn_mfma_f32_16x16x32_bf16(afr[kt], bfr[nt][kt], acc, 0, 0, 0);
            #pragma unroll
            for (int rr = 0; rr < 4; ++rr) {
                float y = acc[rr];
                float sv = y * sigmoid_f(y);               // silu
                long row = rbase + mt*16 + q*4 + rr;       // C: row=(l>>4)*4+reg
                out[row * ND + (w*64 + nt*16 + r)] = sv;   // C: col=l&15
            }
        }
    }
}

// ---------------- Phase 2: serial gated recurrence, 1 block per batch -------
// Wh^T resident in VGPRs as B-frags. A rows replicate h (any C row = answer).
// Round 4: round-1 body, but BOTH vmem ops issued at step start with
// LOAD-BEFORE-STORE program order and INDEX-FORM addressing (alias distance
// provable: rows t+1 vs t-1) so the compiler inserts no store->load
// vmcnt(0), and the barrier's vmcnt(0) drain has ~650cy of MFMA+tail cover.
__global__ __launch_bounds__(256, 1) void scan_kernel(
    const float* __restrict__ Wh, const float* __restrict__ bh,
    float* __restrict__ io /* in: x_silu, out: h_t, in-place */)
{
    __shared__ short hbuf[2][256];
    const int tid = threadIdx.x;
    const int w = tid >> 6;
    const int l = tid & 63;
    const int q = l >> 4, r = l & 15;
    const int b = blockIdx.x;

    // resident B fragments of Wh^T (128 VGPRs)
    bfrag bfr[4][8];
    float bhv0, bhv1, bhv2, bhv3;
    #pragma unroll
    for (int nt = 0; nt < 4; ++nt) {
        int col = w*64 + nt*16 + r;
        float bv = bh[col];
        if (nt == 0) bhv0 = bv; else if (nt == 1) bhv1 = bv;
        else if (nt == 2) bhv2 = bv; else bhv3 = bv;
        const float* wp = Wh + col * ND + q * 8;
        #pragma unroll
        for (int kt = 0; kt < 8; ++kt) {
            f32x4 f0 = *(const f32x4*)(wp + kt*32);
            f32x4 f1 = *(const f32x4*)(wp + kt*32 + 4);
            bfr[nt][kt] = pack8(f0, f1);
        }
    }

    const int j = w*64 + l;                 // this lane's output column == tid
    float* iop = io + (long)b * NS * ND;

    hbuf[0][tid] = 0;                       // h_0 = 0
    __syncthreads();

    float xs_cur  = iop[j];                 // xs[0]
    float hn_prev = 0.0f;                   // h[-1] placeholder

    for (int t = 0; t < NS; ++t) {
        const int cur = t & 1, nxt = cur ^ 1;

        // LDS fragment reads (broadcast, conflict-free)
        bfrag afr[8];
        #pragma unroll
        for (int kt = 0; kt < 8; ++kt)
            afr[kt] = *(const bfrag*)&hbuf[cur][kt*32 + q*8];

        // vmem burst: load xs[t+1] FIRST, then store h[t-1]; index-form rows
        // (clamps are uniform SALU selects, branch-free)
        int trow_l = t + 1 < NS ? t + 1 : NS - 1;   // dummy re-read at last step
        int trow_s = t > 0 ? t - 1 : 0;             // row 0 overwritten at t=1
        float xs_next = iop[(long)trow_l * ND + j];
        iop[(long)trow_s * ND + j] = hn_prev;

        // --- 32 MFMAs: 4 independent K-chains of 8 ---
        f32x4 a0 = {bhv0, bhv0, bhv0, bhv0};
        f32x4 a1 = {bhv1, bhv1, bhv1, bhv1};
        f32x4 a2 = {bhv2, bhv2, bhv2, bhv2};
        f32x4 a3 = {bhv3, bhv3, bhv3, bhv3};
        #pragma unroll
        for (int kt = 0; kt < 8; ++kt) {
            a0 = __builtin_amdgcn_mfma_f32_16x16x32_bf16(afr[kt], bfr[0][kt], a0, 0, 0, 0);
            a1 = __builtin_amdgcn_mfma_f32_16x16x32_bf16(afr[kt], bfr[1][kt], a1, 0, 0, 0);
            a2 = __builtin_amdgcn_mfma_f32_16x16x32_bf16(afr[kt], bfr[2][kt], a2, 0, 0, 0);
            a3 = __builtin_amdgcn_mfma_f32_16x16x32_bf16(afr[kt], bfr[3][kt], a3, 0, 0, 0);
        }

        // --- elementwise tail: 1 value/lane (my tile is nt = q) ---
        float y  = (q & 2) ? ((q & 1) ? a3[0] : a2[0]) : ((q & 1) ? a1[0] : a0[0]);
        float xs = xs_cur;
        float hs = y * sigmoid_f(y);              // silu(h@Wh^T + bh)
        float g  = sigmoid_f(xs + hs);            // gate
        float hn = hs + g * (xs - hs);            // g*xs + (1-g)*hs

        hbuf[nxt][tid] = f2bf(hn);                // h for next step (critical)
        hn_prev = hn;
        xs_cur  = xs_next;
        __syncthreads();
    }
    iop[(long)(NS - 1) * ND + j] = hn_prev;       // final store h[NS-1]
}

// ---------------- Phase 3: in-place LayerNorm over last dim ----------------
__global__ __launch_bounds__(256, 4) void ln_kernel(
    const float* __restrict__ gamma, const float* __restrict__ beta,
    float* __restrict__ io)
{
    const long row = (long)blockIdx.x * 4 + (threadIdx.x >> 6);
    const int l = threadIdx.x & 63;
    float* p = io + row * ND + l * 4;
    f32x4 v = *(const f32x4*)p;
    float s  = v[0] + v[1] + v[2] + v[3];
    float s2 = v[0]*v[0] + v[1]*v[1] + v[2]*v[2] + v[3]*v[3];
    #pragma unroll
    for (int off = 32; off; off >>= 1) {
        s  += __shfl_xor(s,  off, 64);
        s2 += __shfl_xor(s2, off, 64);
    }
    float mu  = s * (1.0f / 256.0f);
    float var = s2 * (1.0f / 256.0f) - mu * mu;
    float inv = __builtin_amdgcn_rsqf(var + 1e-5f);
    f32x4 gm = *(const f32x4*)(gamma + l * 4);
    f32x4 bt = *(const f32x4*)(beta  + l * 4);
    f32x4 o;
    #pragma unroll
    for (int i = 0; i < 4; ++i)
        o[i] = (v[i] - mu) * inv * gm[i] + bt[i];
    *(f32x4*)p = o;
}

extern "C" void kernel_launch(void* const* d_in, const int* in_sizes, int n_in,
                              void* d_out, int out_size, void* d_ws, size_t ws_size,
                              hipStream_t stream) {
    (void)in_sizes; (void)n_in; (void)out_size; (void)d_ws; (void)ws_size;
    const float* x     = (const float*)d_in[0];
    const float* Wx    = (const float*)d_in[1];
    const float* bx    = (const float*)d_in[2];
    const float* Wh    = (const float*)d_in[3];
    const float* bh    = (const float*)d_in[4];
    const float* gamma = (const float*)d_in[5];
    const float* beta  = (const float*)d_in[6];
    float* out = (float*)d_out;

    xproj_kernel<<<(NB * NS) / 64, 256, 0, stream>>>(x, Wx, bx, out);
    scan_kernel <<<NB, 256, 0, stream>>>(Wh, bh, out);
    ln_kernel   <<<(NB * NS) / 4, 256, 0, stream>>>(gamma, beta, out);
}